// Round 3
// baseline (184.021 us; speedup 1.0000x reference)
//
#include <hip/hip_runtime.h>

typedef float floatx4 __attribute__((ext_vector_type(4)));
typedef int intx4 __attribute__((ext_vector_type(4)));

#define GN 4096
#define GK 1024
#define BM 128
#define BN 128
#define BK 64           // K-bytes per LDS tile step -> 16 K-iters, double-buffered
#define INVT (1.0f/0.03f)
#define QS 24.0f        // int8 quant scale; dots <= 1024*127^2 < 2^24 (fp32-exact)
#define NTILES 528      // 32*33/2 upper-tri tiles per modality
#define NCROSS 1024     // 32*32 cross tiles
#define NWG (NCROSS + 2 * NTILES)   // 2080 = 8 * 260

static __device__ __forceinline__ int q8(float x) {
    int v = __float2int_rn(x * QS);
    return v < -127 ? -127 : (v > 127 ? 127 : v);
}

// One block per index i: int8-quantize post-row i AND brand-row i, both
// inv-norms (of quantized ints) and the cross-diag int dot, single pass.
// Also zeroes the accumulators + out (replaces hipMemsetAsync dispatches).
__global__ __launch_bounds__(256)
void prep_all(const float* __restrict__ brand, const float* __restrict__ post,
              unsigned char* __restrict__ brandq, unsigned char* __restrict__ postq,
              float* __restrict__ inv_brand, float* __restrict__ inv_post,
              float* __restrict__ dvec, float* __restrict__ accs,
              float* __restrict__ out) {
    const int i = blockIdx.x, tid = threadIdx.x;
    const int wave = tid >> 6, lane = tid & 63;
    __shared__ float swp[4], swb[4], swd[4];

    float4 pv = ((const float4*)(post  + (size_t)i * GK))[tid];
    float4 bv = ((const float4*)(brand + (size_t)i * GK))[tid];
    int p0 = q8(pv.x), p1 = q8(pv.y), p2 = q8(pv.z), p3 = q8(pv.w);
    int b0 = q8(bv.x), b1 = q8(bv.y), b2 = q8(bv.z), b3 = q8(bv.w);
    ((int*)(postq  + (size_t)i * GK))[tid] =
        (p0 & 255) | ((p1 & 255) << 8) | ((p2 & 255) << 16) | ((p3 & 255) << 24);
    ((int*)(brandq + (size_t)i * GK))[tid] =
        (b0 & 255) | ((b1 & 255) << 8) | ((b2 & 255) << 16) | ((b3 & 255) << 24);

    // per-thread int partials (<= 4*127^2), accumulated as exact-int floats
    float ssp = (float)(p0 * p0 + p1 * p1 + p2 * p2 + p3 * p3);
    float ssb = (float)(b0 * b0 + b1 * b1 + b2 * b2 + b3 * b3);
    float ssd = (float)(p0 * b0 + p1 * b1 + p2 * b2 + p3 * b3);
    #pragma unroll
    for (int off = 32; off > 0; off >>= 1) {
        ssp += __shfl_down(ssp, off);
        ssb += __shfl_down(ssb, off);
        ssd += __shfl_down(ssd, off);
    }
    if (lane == 0) { swp[wave] = ssp; swb[wave] = ssb; swd[wave] = ssd; }
    __syncthreads();
    if (tid == 0) {
        inv_post[i]  = 1.0f / sqrtf(swp[0] + swp[1] + swp[2] + swp[3]);
        inv_brand[i] = 1.0f / sqrtf(swb[0] + swb[1] + swb[2] + swb[3]);
        dvec[i]      = swd[0] + swd[1] + swd[2] + swd[3];
    } else if (tid == 64) {
        accs[i] = 0.f; accs[GN + i] = 0.f; accs[2 * GN + i] = 0.f; accs[3 * GN + i] = 0.f;
        if (i == 0) out[0] = 0.f;
    }
}

// Unified GEMM dispatch, int8 16x16x64 MFMA (2x fp8 rate, exact int scores).
// Double-buffered LDS (2 x 16 KB = 32 KB), BK=64 B per step, 16 K-iters.
// Minimum-2-phase pipeline (T3): per iter {issue next-tile global_load_lds ->
// ds_read+MFMA current buffer -> vmcnt(0); s_barrier}. Staging latency hides
// under the compute phase instead of stalling at the barrier (R0's exposed
// drain). Same occupancy/geometry as R0: 4 waves, 64x64 per wave, ~5 blk/CU.
// LDS rows = 64 B = 4 chunks of 16 B; chunk c of row r at slot c^(r&3);
// inverse swizzle applied to the per-lane GLOBAL source so the DMA writes
// LDS linearly (both-sides-or-neither rule).
#define AS1C (const __attribute__((address_space(1))) void*)
#define AS3C (__attribute__((address_space(3))) void*)

// stage 64-B K-slice k0 of both panels into buffer `buf` (4 instr/wave)
#define STAGE(buf, k0) do { \
    unsigned char* _a = smem + ((buf) << 14) + wave * 2048; \
    unsigned char* _b = _a + BM * BK; \
    _Pragma("unroll") \
    for (int _s = 0; _s < 2; ++_s) { \
        __builtin_amdgcn_global_load_lds(AS1C(aSrc + (size_t)_s * 16 * GK + (k0)), \
                                         AS3C(_a + _s * 1024), 16, 0, 0); \
        __builtin_amdgcn_global_load_lds(AS1C(bSrc + (size_t)_s * 16 * GK + (k0)), \
                                         AS3C(_b + _s * 1024), 16, 0, 0); \
    } \
} while (0)

#define KITER(bufbyte) do { \
    const unsigned char* As_ = smem + (bufbyte); \
    const unsigned char* Bs_ = As_ + BM * BK; \
    intx4 af[4], bfr[4]; \
    _Pragma("unroll") \
    for (int _u = 0; _u < 4; ++_u) \
        bfr[_u] = *(const intx4*)(Bs_ + bOff + _u * 1024); \
    _Pragma("unroll") \
    for (int _m = 0; _m < 4; ++_m) \
        af[_m] = *(const intx4*)(As_ + aOff + _m * 1024); \
    _Pragma("unroll") \
    for (int _t = 0; _t < 4; ++_t) \
        _Pragma("unroll") \
        for (int _u = 0; _u < 4; ++_u) \
            acc[_t][_u] = __builtin_amdgcn_mfma_i32_16x16x64_i8( \
                af[_t], bfr[_u], acc[_t][_u], 0, 0, 0); \
} while (0)

#define DRAIN_BAR() asm volatile("s_waitcnt vmcnt(0)\n\ts_barrier" ::: "memory")

__global__ __launch_bounds__(256, 5)
void gemm_all(const unsigned char* __restrict__ postq, const unsigned char* __restrict__ brandq,
              const float* __restrict__ dvec,
              const float* __restrict__ inv_post, const float* __restrict__ inv_brand,
              float* __restrict__ sum_post, float* __restrict__ cnt_post,
              float* __restrict__ sum_brand, float* __restrict__ cnt_brand) {
    __shared__ __align__(16) unsigned char smem[2 * (BM + BN) * BK];   // 32 KB; epilogue alias

    const int tid = threadIdx.x;
    const int wave = tid >> 6, lane = tid & 63;
    const int wm = (wave >> 1) * 64, wn = (wave & 1) * 64;

    // XCD-bijective block swizzle (2080 = 8 * 260)
    int idx = (int)((blockIdx.x & 7) * (NWG / 8) + (blockIdx.x >> 3));

    const unsigned char *A, *B;
    const float *invA, *invB;
    float *srow, *scol, *crow, *ccol;
    int bm, bn;
    float iaScale;
    bool is_cross, do_cols;

    if (idx < NCROSS) {
        is_cross = true; do_cols = true;
        bm = (idx >> 5) * BM; bn = (idx & 31) * BN;
        A = postq; B = brandq;
        invA = inv_post; invB = inv_brand; iaScale = INVT;
        srow = sum_post; crow = cnt_post; scol = sum_brand; ccol = cnt_brand;
    } else {
        is_cross = false;
        idx -= NCROSS;
        const unsigned char* X; const float* invx; float* sacc;
        if (idx >= NTILES) { idx -= NTILES; X = brandq; invx = inv_brand; sacc = sum_brand; }
        else               {               X = postq;  invx = inv_post;  sacc = sum_post;  }
        int J = (int)((sqrtf(8.f * idx + 1.f) - 1.f) * 0.5f);
        while ((J + 1) * (J + 2) / 2 <= idx) ++J;
        while (J * (J + 1) / 2 > idx) --J;
        const int I = idx - J * (J + 1) / 2;
        bm = I * BM; bn = J * BN;
        A = X; B = X;
        invA = invx; invB = invx; iaScale = 0.8f * INVT;
        srow = sacc; scol = sacc; crow = nullptr; ccol = nullptr;
        do_cols = (I != J);
    }

    const int lrow = lane & 15;
    const int kq = lane >> 4;                 // 0..3

    // DMA: lane l -> row l>>2 (16 rows/instr), LDS slot l&3 (linear dest),
    // global chunk (l&3)^(row&3). Per wave per iter: 2 A + 2 B instructions.
    const size_t dma_off = (size_t)(lane >> 2) * GK
                         + ((((lane & 3) ^ ((lane >> 2) & 3))) * 16);
    const unsigned char* aSrc = A + (size_t)(bm + wave * 32) * GK + dma_off;
    const unsigned char* bSrc = B + (size_t)(bn + wave * 32) * GK + dma_off;

    // fragment read: row = (wm|wn) + m*16 + lrow, chunk = kq ^ (row&3) = kq ^ (lrow&3)
    const int cx = (kq ^ (lrow & 3)) * 16;
    const int aOff = (wm + lrow) * BK + cx;
    const int bOff = (wn + lrow) * BK + cx;

    intx4 acc[4][4] = {};

    STAGE(0, 0);
    DRAIN_BAR();

    #pragma unroll 2
    for (int t = 0; t < 15; ++t) {
        STAGE((t & 1) ^ 1, (t + 1) * BK);   // issue next tile first (latency hides)
        KITER((t & 1) << 14);
        DRAIN_BAR();
    }
    KITER(1 << 14);                          // t = 15, buf 1, nothing left to stage
    __syncthreads();                         // full drain; separates from epilogue alias

    // ---- epilogue (C/D: col=lane&15, row=(lane>>4)*4+reg; shape-determined) ----
    const int cn = lane & 15, rq = lane >> 4;
    float ib_c[4], db_c[4];
    #pragma unroll
    for (int u = 0; u < 4; ++u) {
        const int gc = bn + wn + u * 16 + cn;
        ib_c[u] = invB[gc];
        db_c[u] = is_cross ? dvec[gc] : 0.f;
    }

    float csum[4] = {}, ccnt[4] = {};
    float my_rs = 0.f, my_rc = 0.f;
    #pragma unroll
    for (int t = 0; t < 4; ++t) {
        #pragma unroll
        for (int r = 0; r < 4; ++r) {
            const int rl = wm + t * 16 + rq * 4 + r;
            const int grow = bm + rl;
            const float ia = invA[grow] * iaScale;
            float v = 0.f, w = 0.f;
            if (is_cross) {
                const float da = dvec[grow];
                #pragma unroll
                for (int u = 0; u < 4; ++u) {
                    const float s = (float)acc[t][u][r];   // exact int < 2^24
                    const int gcol = bn + wn + u * 16 + cn;
                    const bool diag = (grow == gcol);
                    float e = __expf(s * ia * ib_c[u]);
                    v += e;
                    csum[u] += e;
                    w += (!diag && s > da) ? 1.f : 0.f;
                    ccnt[u] += (!diag && s > db_c[u]) ? 1.f : 0.f;
                }
                w += __shfl_xor(w, 1); w += __shfl_xor(w, 2);
                w += __shfl_xor(w, 4); w += __shfl_xor(w, 8);
            } else {
                #pragma unroll
                for (int u = 0; u < 4; ++u) {
                    const float s = (float)acc[t][u][r];
                    const int gcol = bn + wn + u * 16 + cn;
                    float e = (grow == gcol) ? 1.0f : __expf(s * ia * ib_c[u]);
                    v += e;
                    csum[u] += e;
                }
            }
            v += __shfl_xor(v, 1); v += __shfl_xor(v, 2);
            v += __shfl_xor(v, 4); v += __shfl_xor(v, 8);
            if (cn == ((t << 2) | r)) { my_rs = v; my_rc = w; }
        }
    }

    // reduction scratch aliases the (dead) tile LDS
    float (*redRS)[2] = (float(*)[2])(smem);
    float (*redRC)[2] = (float(*)[2])(smem + 1024);
    float (*redCS)[2] = (float(*)[2])(smem + 2048);
    float (*redCC)[2] = (float(*)[2])(smem + 3072);

    const int rl_local = wm + (cn >> 2) * 16 + rq * 4 + (cn & 3);
    redRS[rl_local][wave & 1] = my_rs;
    redRC[rl_local][wave & 1] = my_rc;

    float my_cs = 0.f, my_cc = 0.f;
    #pragma unroll
    for (int u = 0; u < 4; ++u) {
        float v = csum[u];
        v += __shfl_xor(v, 16); v += __shfl_xor(v, 32);
        if (rq == u) my_cs = v;
        if (is_cross) {
            float w = ccnt[u];
            w += __shfl_xor(w, 16); w += __shfl_xor(w, 32);
            if (rq == u) my_cc = w;
        }
    }
    const int cl_local = wn + rq * 16 + cn;
    redCS[cl_local][wave >> 1] = my_cs;
    redCC[cl_local][wave >> 1] = my_cc;
    __syncthreads();

    if (tid < 128) {
        atomicAdd(&srow[bm + tid], redRS[tid][0] + redRS[tid][1]);
        if (is_cross) atomicAdd(&crow[bm + tid], redRC[tid][0] + redRC[tid][1]);
    } else if (do_cols) {
        const int t2 = tid - 128;
        atomicAdd(&scol[bn + t2], redCS[t2][0] + redCS[t2][1]);
        if (is_cross) atomicAdd(&ccol[bn + t2], redCC[t2][0] + redCC[t2][1]);
    }
}

// Final per-row loss assembly + global sum
__global__ __launch_bounds__(256)
void final_loss(const float* __restrict__ sum_post, const float* __restrict__ cnt_post,
                const float* __restrict__ sum_brand, const float* __restrict__ cnt_brand,
                const float* __restrict__ dvec,
                const float* __restrict__ inv_post, const float* __restrict__ inv_brand,
                float* __restrict__ out) {
    const int i = blockIdx.x * 256 + threadIdx.x;
    float dl = dvec[i] * inv_post[i] * inv_brand[i] * INVT;
    float lp = logf(sum_post[i]);
    float lb = logf(sum_brand[i]);
    float rp = 1.0f / (4096.0f - cnt_post[i]) + 1.0f;
    float rb = 1.0f / (4096.0f - cnt_brand[i]) + 1.0f;
    float loss = 0.5f * (rb * (lb - dl) + rp * (lp - dl));
    #pragma unroll
    for (int off = 32; off > 0; off >>= 1) loss += __shfl_down(loss, off);
    __shared__ float sw[4];
    int wave = threadIdx.x >> 6, lane = threadIdx.x & 63;
    if (lane == 0) sw[wave] = loss;
    __syncthreads();
    if (threadIdx.x == 0) atomicAdd(out, sw[0] + sw[1] + sw[2] + sw[3]);
}

extern "C" void kernel_launch(void* const* d_in, const int* in_sizes, int n_in,
                              void* d_out, int out_size, void* d_ws, size_t ws_size,
                              hipStream_t stream) {
    const float* brand = (const float*)d_in[0];
    const float* post  = (const float*)d_in[1];
    float* out = (float*)d_out;

    char* ws = (char*)d_ws;
    unsigned char* postq  = (unsigned char*)ws;                          // 4 MB
    unsigned char* brandq = postq + (size_t)GN * GK;                     // 4 MB
    float* inv_post  = (float*)(brandq + (size_t)GN * GK);
    float* inv_brand = inv_post + GN;
    float* dvec      = inv_brand + GN;
    float* accs      = dvec + GN;        // [sum_post, sum_brand, cnt_post, cnt_brand]
    float* sum_post  = accs;
    float* sum_brand = accs + GN;
    float* cnt_post  = accs + 2 * GN;
    float* cnt_brand = accs + 3 * GN;

    prep_all<<<GN, 256, 0, stream>>>(brand, post, brandq, postq,
                                     inv_brand, inv_post, dvec, accs, out);
    gemm_all<<<NWG, 256, 0, stream>>>(postq, brandq, dvec,
                                      inv_post, inv_brand,
                                      sum_post, cnt_post,
                                      sum_brand, cnt_brand);
    final_loss<<<GN / 256, 256, 0, stream>>>(sum_post, cnt_post, sum_brand, cnt_brand,
                                             dvec, inv_post, inv_brand, out);
}

// Round 4
// 132.956 us; speedup vs baseline: 1.3841x; 1.3841x over previous
//
#include <hip/hip_runtime.h>

typedef float floatx4 __attribute__((ext_vector_type(4)));
typedef int intx4 __attribute__((ext_vector_type(4)));

#define GN 4096
#define GK 1024
#define BM 128
#define BN 128
#define BK 64           // K-bytes per LDS step -> 16 iters, TRIPLE-buffered
#define INVT (1.0f/0.03f)
#define QS 24.0f        // int8 quant scale; dots <= 1024*127^2 < 2^24 (fp32-exact)
#define NTILES 528      // 32*33/2 upper-tri tiles per modality
#define NCROSS 1024     // 32*32 cross tiles
#define NWG (NCROSS + 2 * NTILES)   // 2080

static __device__ __forceinline__ int q8(float x) {
    int v = __float2int_rn(x * QS);
    return v < -127 ? -127 : (v > 127 ? 127 : v);
}

// One block per index i: int8-quantize post-row i AND brand-row i, both
// inv-norms (of quantized ints) and the cross-diag int dot, single pass.
// Also zeroes the accumulators + out (replaces hipMemsetAsync dispatches).
__global__ __launch_bounds__(256)
void prep_all(const float* __restrict__ brand, const float* __restrict__ post,
              unsigned char* __restrict__ brandq, unsigned char* __restrict__ postq,
              float* __restrict__ inv_brand, float* __restrict__ inv_post,
              float* __restrict__ dvec, float* __restrict__ accs,
              float* __restrict__ out) {
    const int i = blockIdx.x, tid = threadIdx.x;
    const int wave = tid >> 6, lane = tid & 63;
    __shared__ float swp[4], swb[4], swd[4];

    float4 pv = ((const float4*)(post  + (size_t)i * GK))[tid];
    float4 bv = ((const float4*)(brand + (size_t)i * GK))[tid];
    int p0 = q8(pv.x), p1 = q8(pv.y), p2 = q8(pv.z), p3 = q8(pv.w);
    int b0 = q8(bv.x), b1 = q8(bv.y), b2 = q8(bv.z), b3 = q8(bv.w);
    ((int*)(postq  + (size_t)i * GK))[tid] =
        (p0 & 255) | ((p1 & 255) << 8) | ((p2 & 255) << 16) | ((p3 & 255) << 24);
    ((int*)(brandq + (size_t)i * GK))[tid] =
        (b0 & 255) | ((b1 & 255) << 8) | ((b2 & 255) << 16) | ((b3 & 255) << 24);

    // per-thread int partials (<= 4*127^2), accumulated as exact-int floats
    float ssp = (float)(p0 * p0 + p1 * p1 + p2 * p2 + p3 * p3);
    float ssb = (float)(b0 * b0 + b1 * b1 + b2 * b2 + b3 * b3);
    float ssd = (float)(p0 * b0 + p1 * b1 + p2 * b2 + p3 * b3);
    #pragma unroll
    for (int off = 32; off > 0; off >>= 1) {
        ssp += __shfl_down(ssp, off);
        ssb += __shfl_down(ssb, off);
        ssd += __shfl_down(ssd, off);
    }
    if (lane == 0) { swp[wave] = ssp; swb[wave] = ssb; swd[wave] = ssd; }
    __syncthreads();
    if (tid == 0) {
        inv_post[i]  = 1.0f / sqrtf(swp[0] + swp[1] + swp[2] + swp[3]);
        inv_brand[i] = 1.0f / sqrtf(swb[0] + swb[1] + swb[2] + swb[3]);
        dvec[i]      = swd[0] + swd[1] + swd[2] + swd[3];
    } else if (tid == 64) {
        accs[i] = 0.f; accs[GN + i] = 0.f; accs[2 * GN + i] = 0.f; accs[3 * GN + i] = 0.f;
        if (i == 0) out[0] = 0.f;
    }
}

// Unified GEMM dispatch, int8 16x16x64 MFMA (2x fp8 rate, exact int scores).
// TRIPLE-buffered LDS (3 x 16 KB = 48 KB), BK=64, 16 K-iters, depth-2 DMA
// prefetch with COUNTED vmcnt (T4): per iter {STAGE(t+2) -> ds_read+MFMA(t)
// -> s_waitcnt vmcnt(4); s_barrier}. The wait targets loads issued one full
// iteration earlier -> staging latency fully hidden; vmcnt never drains to 0
// in steady state. 4 waves, 64x64/wave, 3 blocks/CU.
// LDS rows = 64 B = 4 chunks of 16 B; global chunk g of row r at LDS slot
// g ^ ((r>>2)&3): quarter-wave b128 fragment reads hit 8 distinct bank-groups
// x 2 lanes (2-way = free, m136); DMA dest stays linear, with the inverse
// XOR pre-applied to the per-lane GLOBAL source (both-sides-or-neither).
#define AS1C (const __attribute__((address_space(1))) void*)
#define AS3C (__attribute__((address_space(3))) void*)

// stage 64-B K-slice k0 of both panels into buffer b (4 instr/wave, 1 KB each)
#define STAGE(b, k0) do { \
    unsigned char* _a = smem + (b) * 16384 + wave * 2048; \
    __builtin_amdgcn_global_load_lds(AS1C(aSrc + (k0)),           AS3C(_a),        16, 0, 0); \
    __builtin_amdgcn_global_load_lds(AS1C(aSrc + 16 * GK + (k0)), AS3C(_a + 1024), 16, 0, 0); \
    __builtin_amdgcn_global_load_lds(AS1C(bSrc + (k0)),           AS3C(_a + 8192), 16, 0, 0); \
    __builtin_amdgcn_global_load_lds(AS1C(bSrc + 16 * GK + (k0)), AS3C(_a + 9216), 16, 0, 0); \
} while (0)

#define KITER(b) do { \
    const unsigned char* As_ = smem + (b) * 16384; \
    const unsigned char* Bs_ = As_ + 8192; \
    intx4 af[4], bfr[4]; \
    _Pragma("unroll") \
    for (int _u = 0; _u < 4; ++_u) \
        bfr[_u] = *(const intx4*)(Bs_ + bOff + _u * 1024); \
    _Pragma("unroll") \
    for (int _m = 0; _m < 4; ++_m) \
        af[_m] = *(const intx4*)(As_ + aOff + _m * 1024); \
    _Pragma("unroll") \
    for (int _t = 0; _t < 4; ++_t) \
        _Pragma("unroll") \
        for (int _u = 0; _u < 4; ++_u) \
            acc[_t][_u] = __builtin_amdgcn_mfma_i32_16x16x64_i8( \
                af[_t], bfr[_u], acc[_t][_u], 0, 0, 0); \
} while (0)

#define WAITBAR4() asm volatile("s_waitcnt vmcnt(4)\n\ts_barrier" ::: "memory")
#define WAITBAR0() asm volatile("s_waitcnt vmcnt(0)\n\ts_barrier" ::: "memory")

__global__ __launch_bounds__(256, 3)
void gemm_all(const unsigned char* __restrict__ postq, const unsigned char* __restrict__ brandq,
              const float* __restrict__ dvec,
              const float* __restrict__ inv_post, const float* __restrict__ inv_brand,
              float* __restrict__ sum_post, float* __restrict__ cnt_post,
              float* __restrict__ sum_brand, float* __restrict__ cnt_brand) {
    __shared__ __align__(16) unsigned char smem[3 * (BM + BN) * BK];   // 48 KB; epilogue alias

    const int tid = threadIdx.x;
    const int wave = tid >> 6, lane = tid & 63;
    const int wm = (wave >> 1) * 64, wn = (wave & 1) * 64;

    int idx = blockIdx.x;     // R0 dispatch order (no swizzle; locality was good)

    const unsigned char *A, *B;
    const float *invA, *invB;
    float *srow, *scol, *crow, *ccol;
    int bm, bn;
    float iaScale;
    bool is_cross, do_cols;

    if (idx < NCROSS) {
        is_cross = true; do_cols = true;
        bm = (idx >> 5) * BM; bn = (idx & 31) * BN;
        A = postq; B = brandq;
        invA = inv_post; invB = inv_brand; iaScale = INVT;
        srow = sum_post; crow = cnt_post; scol = sum_brand; ccol = cnt_brand;
    } else {
        is_cross = false;
        idx -= NCROSS;
        const unsigned char* X; const float* invx; float* sacc;
        if (idx >= NTILES) { idx -= NTILES; X = brandq; invx = inv_brand; sacc = sum_brand; }
        else               {               X = postq;  invx = inv_post;  sacc = sum_post;  }
        int J = (int)((sqrtf(8.f * idx + 1.f) - 1.f) * 0.5f);
        while ((J + 1) * (J + 2) / 2 <= idx) ++J;
        while (J * (J + 1) / 2 > idx) --J;
        const int I = idx - J * (J + 1) / 2;
        bm = I * BM; bn = J * BN;
        A = X; B = X;
        invA = invx; invB = invx; iaScale = 0.8f * INVT;
        srow = sacc; scol = sacc; crow = nullptr; ccol = nullptr;
        do_cols = (I != J);
    }

    const int lrow = lane & 15;
    const int kq = lane >> 4;                 // 0..3

    // DMA: lane l -> row l>>2 (16 rows/instr), LDS slot l&3 (linear dest),
    // global chunk (l&3)^((l>>4)&3) = slot ^ ((row>>2)&3) since row = base16 + (l>>2).
    const size_t dma_off = (size_t)(lane >> 2) * GK
                         + ((((lane & 3) ^ ((lane >> 4) & 3))) * 16);
    const unsigned char* aSrc = A + (size_t)(bm + wave * 32) * GK + dma_off;
    const unsigned char* bSrc = B + (size_t)(bn + wave * 32) * GK + dma_off;

    // fragment read: row = (wm|wn) + m*16 + lrow -> (row>>2)&3 = (lrow>>2)&3
    const int cx = ((kq ^ ((lrow >> 2) & 3)) * 16);
    const int aOff = (wm + lrow) * BK + cx;
    const int bOff = (wn + lrow) * BK + cx;

    intx4 acc[4][4] = {};

    // prologue: stage tiles 0,1; wait tile 0 only (tile 1 stays in flight)
    STAGE(0, 0); STAGE(1, 64);
    WAITBAR4();

    // steady state: t = 0..11 (stage tiles 2..13), buffers rotate 0,1,2
    #pragma unroll 1
    for (int k = 0; k < 768; k += 192) {
        STAGE(2, k + 128); KITER(0); WAITBAR4();
        STAGE(0, k + 192); KITER(1); WAITBAR4();
        STAGE(1, k + 256); KITER(2); WAITBAR4();
    }
    // tail: t = 12..15
    STAGE(2, 896); KITER(0); WAITBAR4();   // t=12, stage tile 14
    STAGE(0, 960); KITER(1); WAITBAR4();   // t=13, stage tile 15
    KITER(2); WAITBAR0();                  // t=14, drain tile 15
    KITER(0);                              // t=15
    __syncthreads();                       // full drain; separates from epilogue alias

    // ---- epilogue (C/D: col=lane&15, row=(lane>>4)*4+reg; shape-determined) ----
    const int cn = lane & 15, rq = lane >> 4;
    float ib_c[4], db_c[4];
    #pragma unroll
    for (int u = 0; u < 4; ++u) {
        const int gc = bn + wn + u * 16 + cn;
        ib_c[u] = invB[gc];
        db_c[u] = is_cross ? dvec[gc] : 0.f;
    }

    float csum[4] = {}, ccnt[4] = {};
    float my_rs = 0.f, my_rc = 0.f;
    #pragma unroll
    for (int t = 0; t < 4; ++t) {
        #pragma unroll
        for (int r = 0; r < 4; ++r) {
            const int rl = wm + t * 16 + rq * 4 + r;
            const int grow = bm + rl;
            const float ia = invA[grow] * iaScale;
            float v = 0.f, w = 0.f;
            if (is_cross) {
                const float da = dvec[grow];
                #pragma unroll
                for (int u = 0; u < 4; ++u) {
                    const float s = (float)acc[t][u][r];   // exact int < 2^24
                    const int gcol = bn + wn + u * 16 + cn;
                    const bool diag = (grow == gcol);
                    float e = __expf(s * ia * ib_c[u]);
                    v += e;
                    csum[u] += e;
                    w += (!diag && s > da) ? 1.f : 0.f;
                    ccnt[u] += (!diag && s > db_c[u]) ? 1.f : 0.f;
                }
                w += __shfl_xor(w, 1); w += __shfl_xor(w, 2);
                w += __shfl_xor(w, 4); w += __shfl_xor(w, 8);
            } else {
                #pragma unroll
                for (int u = 0; u < 4; ++u) {
                    const float s = (float)acc[t][u][r];
                    const int gcol = bn + wn + u * 16 + cn;
                    float e = (grow == gcol) ? 1.0f : __expf(s * ia * ib_c[u]);
                    v += e;
                    csum[u] += e;
                }
            }
            v += __shfl_xor(v, 1); v += __shfl_xor(v, 2);
            v += __shfl_xor(v, 4); v += __shfl_xor(v, 8);
            if (cn == ((t << 2) | r)) { my_rs = v; my_rc = w; }
        }
    }

    // reduction scratch aliases the (dead) tile LDS
    float (*redRS)[2] = (float(*)[2])(smem);
    float (*redRC)[2] = (float(*)[2])(smem + 1024);
    float (*redCS)[2] = (float(*)[2])(smem + 2048);
    float (*redCC)[2] = (float(*)[2])(smem + 3072);

    const int rl_local = wm + (cn >> 2) * 16 + rq * 4 + (cn & 3);
    redRS[rl_local][wave & 1] = my_rs;
    redRC[rl_local][wave & 1] = my_rc;

    float my_cs = 0.f, my_cc = 0.f;
    #pragma unroll
    for (int u = 0; u < 4; ++u) {
        float v = csum[u];
        v += __shfl_xor(v, 16); v += __shfl_xor(v, 32);
        if (rq == u) my_cs = v;
        if (is_cross) {
            float w = ccnt[u];
            w += __shfl_xor(w, 16); w += __shfl_xor(w, 32);
            if (rq == u) my_cc = w;
        }
    }
    const int cl_local = wn + rq * 16 + cn;
    redCS[cl_local][wave >> 1] = my_cs;
    redCC[cl_local][wave >> 1] = my_cc;
    __syncthreads();

    if (tid < 128) {
        atomicAdd(&srow[bm + tid], redRS[tid][0] + redRS[tid][1]);
        if (is_cross) atomicAdd(&crow[bm + tid], redRC[tid][0] + redRC[tid][1]);
    } else if (do_cols) {
        const int t2 = tid - 128;
        atomicAdd(&scol[bn + t2], redCS[t2][0] + redCS[t2][1]);
        if (is_cross) atomicAdd(&ccol[bn + t2], redCC[t2][0] + redCC[t2][1]);
    }
}

// Final per-row loss assembly + global sum
__global__ __launch_bounds__(256)
void final_loss(const float* __restrict__ sum_post, const float* __restrict__ cnt_post,
                const float* __restrict__ sum_brand, const float* __restrict__ cnt_brand,
                const float* __restrict__ dvec,
                const float* __restrict__ inv_post, const float* __restrict__ inv_brand,
                float* __restrict__ out) {
    const int i = blockIdx.x * 256 + threadIdx.x;
    float dl = dvec[i] * inv_post[i] * inv_brand[i] * INVT;
    float lp = logf(sum_post[i]);
    float lb = logf(sum_brand[i]);
    float rp = 1.0f / (4096.0f - cnt_post[i]) + 1.0f;
    float rb = 1.0f / (4096.0f - cnt_brand[i]) + 1.0f;
    float loss = 0.5f * (rb * (lb - dl) + rp * (lp - dl));
    #pragma unroll
    for (int off = 32; off > 0; off >>= 1) loss += __shfl_down(loss, off);
    __shared__ float sw[4];
    int wave = threadIdx.x >> 6, lane = threadIdx.x & 63;
    if (lane == 0) sw[wave] = loss;
    __syncthreads();
    if (threadIdx.x == 0) atomicAdd(out, sw[0] + sw[1] + sw[2] + sw[3]);
}

extern "C" void kernel_launch(void* const* d_in, const int* in_sizes, int n_in,
                              void* d_out, int out_size, void* d_ws, size_t ws_size,
                              hipStream_t stream) {
    const float* brand = (const float*)d_in[0];
    const float* post  = (const float*)d_in[1];
    float* out = (float*)d_out;

    char* ws = (char*)d_ws;
    unsigned char* postq  = (unsigned char*)ws;                          // 4 MB
    unsigned char* brandq = postq + (size_t)GN * GK;                     // 4 MB
    float* inv_post  = (float*)(brandq + (size_t)GN * GK);
    float* inv_brand = inv_post + GN;
    float* dvec      = inv_brand + GN;
    float* accs      = dvec + GN;        // [sum_post, sum_brand, cnt_post, cnt_brand]
    float* sum_post  = accs;
    float* sum_brand = accs + GN;
    float* cnt_post  = accs + 2 * GN;
    float* cnt_brand = accs + 3 * GN;

    prep_all<<<GN, 256, 0, stream>>>(brand, post, brandq, postq,
                                     inv_brand, inv_post, dvec, accs, out);
    gemm_all<<<NWG, 256, 0, stream>>>(postq, brandq, dvec,
                                      inv_post, inv_brand,
                                      sum_post, cnt_post,
                                      sum_brand, cnt_brand);
    final_loss<<<GN / 256, 256, 0, stream>>>(sum_post, cnt_post, sum_brand, cnt_brand,
                                             dvec, inv_post, inv_brand, out);
}